// Round 1
// baseline (1964.849 us; speedup 1.0000x reference)
//
#include <hip/hip_runtime.h>
#include <stdint.h>

// TopK SAE forward, MI355X/gfx950.
// Strategy: bf16-MFMA approximate encoder -> per-row candidate band (margin 0.03)
// -> exact fp64 recompute of ~83 candidates/row -> true top-64 (index tie-break)
// -> zero+scatter z, sparse decoder with pre-transposed bf16 W_dec.

#define M_BATCH 8192
#define K_DIM   1024
#define N_LAT   16384
#define TOPK    64
#define CAND_CAP 256
#define MARGIN  0.03f

typedef float f32x4 __attribute__((ext_vector_type(4)));
typedef short s16x8 __attribute__((ext_vector_type(8)));

typedef __attribute__((address_space(3))) void       lds_void;
typedef const __attribute__((address_space(1))) void glb_void;

__device__ __forceinline__ void async_copy16(const void* g, void* l) {
    __builtin_amdgcn_global_load_lds((glb_void*)g, (lds_void*)l, 16, 0, 0);
}

__device__ __forceinline__ unsigned short f2bf(float f) {
    uint32_t u = __float_as_uint(f);
    uint32_t r = (u + 0x7FFFu + ((u >> 16) & 1u)) >> 16;   // RNE
    return (unsigned short)r;
}
__device__ __forceinline__ float bf2f(unsigned short h) {
    return __uint_as_float(((uint32_t)h) << 16);
}

// ---------------- K0a: fp32 -> bf16 conversion (vectorized) ----------------
__global__ void to_bf16(const float4* __restrict__ src, unsigned short* __restrict__ dst,
                        int nvec) {
    int i = blockIdx.x * blockDim.x + threadIdx.x;
    if (i < nvec) {
        float4 f = src[i];
        ushort4 o;
        o.x = f2bf(f.x); o.y = f2bf(f.y); o.z = f2bf(f.z); o.w = f2bf(f.w);
        *(ushort4*)(dst + (size_t)i * 4) = o;
    }
}

// ---------------- K0b: W_dec [1024,16384] fp32 -> W_decT [16384,1024] bf16 ----------------
__global__ void transpose_wdec(const float* __restrict__ Wd, unsigned short* __restrict__ WdT) {
    __shared__ float tile[64][65];
    int bj = blockIdx.x;  // 0..255  (latent dim blocks)
    int bi = blockIdx.y;  // 0..15   (input dim blocks)
    int t = threadIdx.x;
    int tj = t & 63, ti4 = t >> 6;
    #pragma unroll
    for (int rr = 0; rr < 16; rr++) {
        int i = ti4 * 16 + rr;
        tile[i][tj] = Wd[(size_t)(bi * 64 + i) * N_LAT + bj * 64 + tj];
    }
    __syncthreads();
    int ti = t & 63, tj4 = t >> 6;
    #pragma unroll
    for (int rr = 0; rr < 16; rr++) {
        int j = tj4 * 16 + rr;
        WdT[(size_t)(bj * 64 + j) * K_DIM + bi * 64 + ti] = f2bf(tile[ti][j]);
    }
}

// ---------------- K1: bf16 MFMA encoder GEMM (m97 structure, NT) ----------------
// A = xh [M,K] bf16, B = Wh [N,K] bf16, Z[m,n] = sum_k A[m,k]*B[n,k] + b_enc[n]
__global__ __launch_bounds__(256, 3) void enc_gemm(
        const unsigned short* __restrict__ A,
        const unsigned short* __restrict__ B,
        const float* __restrict__ b_enc,
        float* __restrict__ Z) {
    __shared__ unsigned short aT[128 * 32];
    __shared__ unsigned short bT[128 * 32];
    int bn = blockIdx.x;            // 0..127
    int bm = blockIdx.y;            // 0..63
    int t = threadIdx.x;
    int w = t >> 6, l = t & 63;
    int wm = (w >> 1) * 64, wn = (w & 1) * 64;
    int lm = l & 15, q = l >> 4;

    const unsigned short* gA = A + (size_t)(bm * 128) * K_DIM;
    const unsigned short* gB = B + (size_t)(bn * 128) * K_DIM;

    f32x4 acc[4][4];
    #pragma unroll
    for (int i = 0; i < 4; i++)
        #pragma unroll
        for (int j = 0; j < 4; j++) acc[i][j] = (f32x4)0.0f;

    int srow = t >> 2;          // 0..63 staging row
    int sk = (t & 3) * 8;       // staging k offset (elements)

    for (int kt = 0; kt < K_DIM; kt += 32) {
        // stage A tile (128x32) and B tile (128x32): LDS dest offset == 16*t per issue
        async_copy16(gA + (size_t)srow * K_DIM + kt + sk, &aT[t * 8]);
        async_copy16(gA + (size_t)(srow + 64) * K_DIM + kt + sk, &aT[2048 + t * 8]);
        async_copy16(gB + (size_t)srow * K_DIM + kt + sk, &bT[t * 8]);
        async_copy16(gB + (size_t)(srow + 64) * K_DIM + kt + sk, &bT[2048 + t * 8]);
        __syncthreads();   // compiler drains vmcnt before s_barrier

        s16x8 af[4], bf[4];
        #pragma unroll
        for (int mi = 0; mi < 4; mi++)
            af[mi] = *(const s16x8*)&aT[(wm + mi * 16 + lm) * 32 + q * 8];
        #pragma unroll
        for (int ni = 0; ni < 4; ni++)
            bf[ni] = *(const s16x8*)&bT[(wn + ni * 16 + lm) * 32 + q * 8];
        #pragma unroll
        for (int mi = 0; mi < 4; mi++)
            #pragma unroll
            for (int ni = 0; ni < 4; ni++)
                acc[mi][ni] = __builtin_amdgcn_mfma_f32_16x16x32_bf16(
                    af[mi], bf[ni], acc[mi][ni], 0, 0, 0);
        __syncthreads();
    }

    // Epilogue: D layout col = lane&15, row = q*4 + r (m89-verified)
    size_t gm0 = (size_t)bm * 128 + wm;
    size_t gn0 = (size_t)bn * 128 + wn;
    #pragma unroll
    for (int ni = 0; ni < 4; ni++) {
        size_t gn = gn0 + ni * 16 + lm;
        float bv = b_enc[gn];
        #pragma unroll
        for (int mi = 0; mi < 4; mi++) {
            size_t gmb = gm0 + mi * 16 + q * 4;
            #pragma unroll
            for (int r = 0; r < 4; r++)
                Z[(gmb + r) * N_LAT + gn] = acc[mi][ni][r] + bv;
        }
    }
}

// ---------------- K2: per-row radix select + candidate collection ----------------
__global__ void select_cand(const float* __restrict__ Z, int* __restrict__ cand,
                            int* __restrict__ cnt) {
    int r = blockIdx.x;
    const float* z = Z + (size_t)r * N_LAT;
    __shared__ int hist[256];
    __shared__ int s_above, s_b1, s_b2, s_cn;
    int t = threadIdx.x;

    hist[t] = 0;
    __syncthreads();
    for (int i = t; i < N_LAT; i += 256) {
        uint32_t u = __float_as_uint(z[i]);
        uint32_t key = (u & 0x80000000u) ? ~u : (u | 0x80000000u);
        atomicAdd(&hist[key >> 24], 1);
    }
    __syncthreads();
    if (t == 0) {
        int c = 0, b = 255;
        for (; b > 0; b--) { if (c + hist[b] >= TOPK) break; c += hist[b]; }
        s_above = c; s_b1 = b;
    }
    __syncthreads();
    int B1 = s_b1, AB = s_above;
    hist[t] = 0;
    __syncthreads();
    for (int i = t; i < N_LAT; i += 256) {
        uint32_t u = __float_as_uint(z[i]);
        uint32_t key = (u & 0x80000000u) ? ~u : (u | 0x80000000u);
        if ((int)(key >> 24) == B1) atomicAdd(&hist[(key >> 16) & 255], 1);
    }
    __syncthreads();
    if (t == 0) {
        int c = AB, b = 255;
        for (; b > 0; b--) { if (c + hist[b] >= TOPK) break; c += hist[b]; }
        s_b2 = b; s_cn = 0;
    }
    __syncthreads();
    uint32_t prefix = ((uint32_t)B1 << 24) | ((uint32_t)s_b2 << 16);
    uint32_t ub = (prefix & 0x80000000u) ? (prefix ^ 0x80000000u) : ~prefix;
    float cut = __uint_as_float(ub) - MARGIN;   // lower bound of 64th-value bucket - margin
    for (int i = t; i < N_LAT; i += 256) {
        if (z[i] >= cut) {
            int p = atomicAdd(&s_cn, 1);
            if (p < CAND_CAP) cand[(size_t)r * CAND_CAP + p] = i;
        }
    }
    __syncthreads();
    if (t == 0) cnt[r] = min(s_cn, CAND_CAP);
}

// ---------------- K3: exact fp64 recompute of candidates + true top-64 ----------------
__global__ void exact_topk(const float* __restrict__ x, const float* __restrict__ W,
                           const float* __restrict__ b_enc,
                           const int* __restrict__ cand, const int* __restrict__ cnt,
                           int* __restrict__ seli, float* __restrict__ selv) {
    int r = blockIdx.x;
    __shared__ float xs[K_DIM];
    __shared__ double vals[CAND_CAP];
    __shared__ int ns[CAND_CAP];
    int t = threadIdx.x;
    const float* xr = x + (size_t)r * K_DIM;
    for (int i = t; i < K_DIM; i += 256) xs[i] = xr[i];
    int n_c = cnt[r];
    if (t < n_c) ns[t] = cand[(size_t)r * CAND_CAP + t];
    __syncthreads();

    int w = t >> 6, l = t & 63;
    for (int c = w; c < n_c; c += 4) {
        int n = ns[c];
        const float* wr = W + (size_t)n * K_DIM;
        double s = 0.0;
        #pragma unroll
        for (int i = 0; i < K_DIM / 64; i++)
            s += (double)xs[l + i * 64] * (double)wr[l + i * 64];
        for (int o = 32; o > 0; o >>= 1) s += __shfl_down(s, o, 64);
        if (l == 0) vals[c] = s + (double)b_enc[n];
    }
    __syncthreads();

    if (t < n_c) {
        double v = vals[t];
        int n = ns[t];
        int rank = 0;
        for (int j = 0; j < n_c; j++) {
            double vj = vals[j];
            if (vj > v || (vj == v && ns[j] < n)) rank++;   // lax.top_k tie-break: lower index first
        }
        if (rank < TOPK) {
            seli[(size_t)r * TOPK + rank] = n;
            selv[(size_t)r * TOPK + rank] = (float)(v > 0.0 ? v : 0.0);
        }
    }
}

// ---------------- K4: zero z region ----------------
__global__ void zero_z(float4* __restrict__ p, size_t nvec) {
    size_t i = (size_t)blockIdx.x * blockDim.x + threadIdx.x;
    size_t stride = (size_t)gridDim.x * blockDim.x;
    for (; i < nvec; i += stride) p[i] = make_float4(0.f, 0.f, 0.f, 0.f);
}

// ---------------- K5: scatter z + sparse decoder ----------------
__global__ void decode(const int* __restrict__ seli, const float* __restrict__ selv,
                       const unsigned short* __restrict__ WdT,
                       const float* __restrict__ b_dec,
                       float* __restrict__ recon, float* __restrict__ Z) {
    int r = blockIdx.x;
    __shared__ int is[TOPK];
    __shared__ float vs[TOPK];
    int t = threadIdx.x;
    if (t < TOPK) {
        is[t] = seli[(size_t)r * TOPK + t];
        vs[t] = selv[(size_t)r * TOPK + t];
    }
    __syncthreads();
    if (t < TOPK) Z[(size_t)r * N_LAT + is[t]] = vs[t];

    float4 acc = make_float4(0.f, 0.f, 0.f, 0.f);
    #pragma unroll 4
    for (int j = 0; j < TOPK; j++) {
        const unsigned short* wr = WdT + (size_t)is[j] * K_DIM;
        float v = vs[j];
        ushort4 w4 = *(const ushort4*)(wr + 4 * t);
        acc.x += v * bf2f(w4.x);
        acc.y += v * bf2f(w4.y);
        acc.z += v * bf2f(w4.z);
        acc.w += v * bf2f(w4.w);
    }
    float4 bd = *(const float4*)(b_dec + 4 * t);
    acc.x += bd.x; acc.y += bd.y; acc.z += bd.z; acc.w += bd.w;
    *(float4*)(recon + (size_t)r * K_DIM + 4 * t) = acc;
}

// ---------------- launch ----------------
extern "C" void kernel_launch(void* const* d_in, const int* in_sizes, int n_in,
                              void* d_out, int out_size, void* d_ws, size_t ws_size,
                              hipStream_t stream) {
    const float* x     = (const float*)d_in[0];
    const float* W_enc = (const float*)d_in[1];
    const float* b_enc = (const float*)d_in[2];
    const float* W_dec = (const float*)d_in[3];
    const float* b_dec = (const float*)d_in[4];
    float* recon = (float*)d_out;
    float* Z     = recon + (size_t)M_BATCH * K_DIM;   // z region of d_out (also GEMM scratch)

    char* ws = (char*)d_ws;
    unsigned short* Wh  = (unsigned short*)(ws);                 // 33,554,432 B
    unsigned short* xh  = (unsigned short*)(ws + 33554432);      // 16,777,216 B
    unsigned short* WdT = (unsigned short*)(ws + 50331648);      // 33,554,432 B
    int*   cand = (int*)  (ws + 83886080);                       //  8,388,608 B
    int*   cnt  = (int*)  (ws + 92274688);                       //     32,768 B
    int*   seli = (int*)  (ws + 92307456);                       //  2,097,152 B
    float* selv = (float*)(ws + 94404608);                       //  2,097,152 B
    // total 96,501,760 B

    // K0: convert + transpose
    to_bf16<<<(N_LAT * K_DIM / 4 + 255) / 256, 256, 0, stream>>>(
        (const float4*)W_enc, Wh, N_LAT * K_DIM / 4);
    to_bf16<<<(M_BATCH * K_DIM / 4 + 255) / 256, 256, 0, stream>>>(
        (const float4*)x, xh, M_BATCH * K_DIM / 4);
    transpose_wdec<<<dim3(N_LAT / 64, K_DIM / 64), 256, 0, stream>>>(W_dec, WdT);

    // K1: approximate encoder GEMM -> Z (fp32 scratch in d_out)
    enc_gemm<<<dim3(N_LAT / 128, M_BATCH / 128), 256, 0, stream>>>(xh, Wh, b_enc, Z);

    // K2: per-row candidate band
    select_cand<<<M_BATCH, 256, 0, stream>>>(Z, cand, cnt);

    // K3: exact fp64 recompute + true top-64
    exact_topk<<<M_BATCH, 256, 0, stream>>>(x, W_enc, b_enc, cand, cnt, seli, selv);

    // K4: zero z, K5: scatter + decode
    zero_z<<<16384, 256, 0, stream>>>((float4*)Z, (size_t)M_BATCH * N_LAT / 4);
    decode<<<M_BATCH, 256, 0, stream>>>(seli, selv, WdT, b_dec, recon, Z);
}

// Round 2
// 1834.953 us; speedup vs baseline: 1.0708x; 1.0708x over previous
//
#include <hip/hip_runtime.h>
#include <stdint.h>

// TopK SAE forward, MI355X/gfx950.
// bf16-MFMA approximate encoder -> single-pass LDS-staged candidate select
// (1024 linear bins + parallel suffix scan, margin 0.03) -> exact fp64
// recompute of ~90 candidates/row -> true top-64 (index tie-break) ->
// fused zero+scatter+sparse-decode with pre-transposed bf16 W_dec.

#define M_BATCH 8192
#define K_DIM   1024
#define N_LAT   16384
#define TOPK    64
#define CAND_CAP 256
#define MARGIN  0.03f

typedef float f32x4 __attribute__((ext_vector_type(4)));
typedef short s16x8 __attribute__((ext_vector_type(8)));

typedef __attribute__((address_space(3))) void       lds_void;
typedef const __attribute__((address_space(1))) void glb_void;

__device__ __forceinline__ void async_copy16(const void* g, void* l) {
    __builtin_amdgcn_global_load_lds((glb_void*)g, (lds_void*)l, 16, 0, 0);
}

__device__ __forceinline__ unsigned short f2bf(float f) {
    uint32_t u = __float_as_uint(f);
    uint32_t r = (u + 0x7FFFu + ((u >> 16) & 1u)) >> 16;   // RNE
    return (unsigned short)r;
}
__device__ __forceinline__ float bf2f(unsigned short h) {
    return __uint_as_float(((uint32_t)h) << 16);
}

// ---------------- K0a: fp32 -> bf16 conversion (vectorized) ----------------
__global__ void to_bf16(const float4* __restrict__ src, unsigned short* __restrict__ dst,
                        int nvec) {
    int i = blockIdx.x * blockDim.x + threadIdx.x;
    if (i < nvec) {
        float4 f = src[i];
        ushort4 o;
        o.x = f2bf(f.x); o.y = f2bf(f.y); o.z = f2bf(f.z); o.w = f2bf(f.w);
        *(ushort4*)(dst + (size_t)i * 4) = o;
    }
}

// ---------------- K0b: W_dec [1024,16384] fp32 -> W_decT [16384,1024] bf16 ----------------
__global__ void transpose_wdec(const float* __restrict__ Wd, unsigned short* __restrict__ WdT) {
    __shared__ float tile[64][65];
    int bj = blockIdx.x;  // latent blocks
    int bi = blockIdx.y;  // input blocks
    int t = threadIdx.x;
    int tj = t & 63, ti4 = t >> 6;
    #pragma unroll
    for (int rr = 0; rr < 16; rr++) {
        int i = ti4 * 16 + rr;
        tile[i][tj] = Wd[(size_t)(bi * 64 + i) * N_LAT + bj * 64 + tj];
    }
    __syncthreads();
    int ti = t & 63, tj4 = t >> 6;
    #pragma unroll
    for (int rr = 0; rr < 16; rr++) {
        int j = tj4 * 16 + rr;
        WdT[(size_t)(bj * 64 + j) * K_DIM + bi * 64 + ti] = f2bf(tile[ti][j]);
    }
}

// ---------------- K1: bf16 MFMA encoder GEMM (m97 structure, NT) ----------------
__global__ __launch_bounds__(256, 3) void enc_gemm(
        const unsigned short* __restrict__ A,
        const unsigned short* __restrict__ B,
        const float* __restrict__ b_enc,
        float* __restrict__ Z) {
    __shared__ unsigned short aT[128 * 32];
    __shared__ unsigned short bT[128 * 32];
    int bn = blockIdx.x;
    int bm = blockIdx.y;
    int t = threadIdx.x;
    int w = t >> 6, l = t & 63;
    int wm = (w >> 1) * 64, wn = (w & 1) * 64;
    int lm = l & 15, q = l >> 4;

    const unsigned short* gA = A + (size_t)(bm * 128) * K_DIM;
    const unsigned short* gB = B + (size_t)(bn * 128) * K_DIM;

    f32x4 acc[4][4];
    #pragma unroll
    for (int i = 0; i < 4; i++)
        #pragma unroll
        for (int j = 0; j < 4; j++) acc[i][j] = (f32x4)0.0f;

    int srow = t >> 2;
    int sk = (t & 3) * 8;

    for (int kt = 0; kt < K_DIM; kt += 32) {
        async_copy16(gA + (size_t)srow * K_DIM + kt + sk, &aT[t * 8]);
        async_copy16(gA + (size_t)(srow + 64) * K_DIM + kt + sk, &aT[2048 + t * 8]);
        async_copy16(gB + (size_t)srow * K_DIM + kt + sk, &bT[t * 8]);
        async_copy16(gB + (size_t)(srow + 64) * K_DIM + kt + sk, &bT[2048 + t * 8]);
        __syncthreads();

        s16x8 af[4], bf[4];
        #pragma unroll
        for (int mi = 0; mi < 4; mi++)
            af[mi] = *(const s16x8*)&aT[(wm + mi * 16 + lm) * 32 + q * 8];
        #pragma unroll
        for (int ni = 0; ni < 4; ni++)
            bf[ni] = *(const s16x8*)&bT[(wn + ni * 16 + lm) * 32 + q * 8];
        #pragma unroll
        for (int mi = 0; mi < 4; mi++)
            #pragma unroll
            for (int ni = 0; ni < 4; ni++)
                acc[mi][ni] = __builtin_amdgcn_mfma_f32_16x16x32_bf16(
                    af[mi], bf[ni], acc[mi][ni], 0, 0, 0);
        __syncthreads();
    }

    size_t gm0 = (size_t)bm * 128 + wm;
    size_t gn0 = (size_t)bn * 128 + wn;
    #pragma unroll
    for (int ni = 0; ni < 4; ni++) {
        size_t gn = gn0 + ni * 16 + lm;
        float bv = b_enc[gn];
        #pragma unroll
        for (int mi = 0; mi < 4; mi++) {
            size_t gmb = gm0 + mi * 16 + q * 4;
            #pragma unroll
            for (int r = 0; r < 4; r++)
                Z[(gmb + r) * N_LAT + gn] = acc[mi][ni][r] + bv;
        }
    }
}

// ---------------- K2 v2: single-pass LDS-staged candidate select ----------------
// One block per row. Stage 64 KB row in LDS while histogramming into 1024
// linear bins (2 copies, wave-pair each). Parallel suffix scan finds the
// bucket holding the 64th value; collect from LDS.
__global__ __launch_bounds__(256) void select_cand(
        const float* __restrict__ Z, int* __restrict__ cand, int* __restrict__ cnt) {
    __shared__ float zrow[N_LAT / 4 * 4];          // 64 KB (filled fully)
    __shared__ int hist[2][1024];                  // 8 KB
    __shared__ int wsum[4];
    __shared__ int s_above, s_bin;
    __shared__ int s_cn;
    __shared__ float s_cut;

    int r = blockIdx.x;
    int t = threadIdx.x;
    int w = t >> 6, l = t & 63;
    int hc = w >> 1;                               // wave-pair histogram copy

    #pragma unroll
    for (int i = 0; i < 4; i++) {
        hist[0][t + i * 256] = 0;
        hist[1][t + i * 256] = 0;
    }
    __syncthreads();

    const float4* zg = (const float4*)(Z + (size_t)r * N_LAT);
    #pragma unroll
    for (int it = 0; it < 16; it++) {
        int vi = t + it * 256;                     // float4 index
        float4 v = zg[vi];
        *(float4*)&zrow[vi * 4] = v;
        int b0 = min(max((int)(v.x * 64.0f), 0), 1023);
        int b1 = min(max((int)(v.y * 64.0f), 0), 1023);
        int b2 = min(max((int)(v.z * 64.0f), 0), 1023);
        int b3 = min(max((int)(v.w * 64.0f), 0), 1023);
        atomicAdd(&hist[hc][b0], 1);
        atomicAdd(&hist[hc][b1], 1);
        atomicAdd(&hist[hc][b2], 1);
        atomicAdd(&hist[hc][b3], 1);
    }
    __syncthreads();

    // merge copies; thread t owns bins {t, t+256, t+512, t+768}
    #pragma unroll
    for (int i = 0; i < 4; i++) {
        int b = t + i * 256;
        hist[0][b] += hist[1][b];
    }
    __syncthreads();

    // group sums: thread t owns bins 4t..4t+3
    int g = hist[0][t * 4] + hist[0][t * 4 + 1] + hist[0][t * 4 + 2] + hist[0][t * 4 + 3];

    // block-wide inclusive prefix of g over t (low->high)
    int val = g;
    #pragma unroll
    for (int d = 1; d < 64; d <<= 1) {
        int n = __shfl_up(val, d, 64);
        if (l >= d) val += n;
    }
    if (l == 63) wsum[w] = val;
    __syncthreads();
    int off = 0;
    for (int i = 0; i < w; i++) off += wsum[i];
    int total = wsum[0] + wsum[1] + wsum[2] + wsum[3];
    int incl = val + off;
    int above = total - incl;                      // elements in groups strictly above t
    if (above < TOPK && above + g >= TOPK) {       // exactly one thread
        s_above = above;
        s_bin = t;
    }
    __syncthreads();
    if (t == 0) {
        int c = s_above;
        int b = s_bin * 4 + 3;
        for (; b > s_bin * 4; b--) {
            if (c + hist[0][b] >= TOPK) break;
            c += hist[0][b];
        }
        s_cut = (float)b * (1.0f / 64.0f) - MARGIN;
        s_cn = 0;
    }
    __syncthreads();

    float cut = s_cut;
    #pragma unroll
    for (int it = 0; it < 16; it++) {
        int vi = t + it * 256;
        float4 v = *(const float4*)&zrow[vi * 4];
        if (v.x >= cut) { int p = atomicAdd(&s_cn, 1); if (p < CAND_CAP) cand[(size_t)r * CAND_CAP + p] = vi * 4; }
        if (v.y >= cut) { int p = atomicAdd(&s_cn, 1); if (p < CAND_CAP) cand[(size_t)r * CAND_CAP + p] = vi * 4 + 1; }
        if (v.z >= cut) { int p = atomicAdd(&s_cn, 1); if (p < CAND_CAP) cand[(size_t)r * CAND_CAP + p] = vi * 4 + 2; }
        if (v.w >= cut) { int p = atomicAdd(&s_cn, 1); if (p < CAND_CAP) cand[(size_t)r * CAND_CAP + p] = vi * 4 + 3; }
    }
    __syncthreads();
    if (t == 0) cnt[r] = min(s_cn, CAND_CAP);
}

// ---------------- K3: exact fp64 recompute of candidates + true top-64 ----------------
__global__ void exact_topk(const float* __restrict__ x, const float* __restrict__ W,
                           const float* __restrict__ b_enc,
                           const int* __restrict__ cand, const int* __restrict__ cnt,
                           int* __restrict__ seli, float* __restrict__ selv) {
    int r = blockIdx.x;
    __shared__ float xs[K_DIM];
    __shared__ double vals[CAND_CAP];
    __shared__ int ns[CAND_CAP];
    int t = threadIdx.x;
    const float* xr = x + (size_t)r * K_DIM;
    for (int i = t; i < K_DIM; i += 256) xs[i] = xr[i];
    int n_c = cnt[r];
    if (t < n_c) ns[t] = cand[(size_t)r * CAND_CAP + t];
    __syncthreads();

    int w = t >> 6, l = t & 63;
    for (int c = w; c < n_c; c += 4) {
        int n = ns[c];
        const float* wr = W + (size_t)n * K_DIM;
        double s = 0.0;
        #pragma unroll
        for (int i = 0; i < K_DIM / 64; i++)
            s += (double)xs[l + i * 64] * (double)wr[l + i * 64];
        for (int o = 32; o > 0; o >>= 1) s += __shfl_down(s, o, 64);
        if (l == 0) vals[c] = s + (double)b_enc[n];
    }
    __syncthreads();

    if (t < n_c) {
        double v = vals[t];
        int n = ns[t];
        int rank = 0;
        for (int j = 0; j < n_c; j++) {
            double vj = vals[j];
            if (vj > v || (vj == v && ns[j] < n)) rank++;   // lax.top_k tie-break
        }
        if (rank < TOPK) {
            seli[(size_t)r * TOPK + rank] = n;
            selv[(size_t)r * TOPK + rank] = (float)(v > 0.0 ? v : 0.0);
        }
    }
}

// ---------------- K4: fused zero-z + scatter + sparse decoder ----------------
__global__ void decode(const int* __restrict__ seli, const float* __restrict__ selv,
                       const unsigned short* __restrict__ WdT,
                       const float* __restrict__ b_dec,
                       float* __restrict__ recon, float* __restrict__ Z) {
    int r = blockIdx.x;
    __shared__ int is[TOPK];
    __shared__ float vs[TOPK];
    int t = threadIdx.x;
    if (t < TOPK) {
        is[t] = seli[(size_t)r * TOPK + t];
        vs[t] = selv[(size_t)r * TOPK + t];
    }
    // zero this row's z (full-line streaming writes)
    float4* zr4 = (float4*)(Z + (size_t)r * N_LAT);
    float4 z4 = make_float4(0.f, 0.f, 0.f, 0.f);
    #pragma unroll
    for (int it = 0; it < 16; it++) zr4[t + it * 256] = z4;
    __syncthreads();
    if (t < TOPK) Z[(size_t)r * N_LAT + is[t]] = vs[t];

    float4 acc = make_float4(0.f, 0.f, 0.f, 0.f);
    #pragma unroll 4
    for (int j = 0; j < TOPK; j++) {
        const unsigned short* wr = WdT + (size_t)is[j] * K_DIM;
        float v = vs[j];
        ushort4 w4 = *(const ushort4*)(wr + 4 * t);
        acc.x += v * bf2f(w4.x);
        acc.y += v * bf2f(w4.y);
        acc.z += v * bf2f(w4.z);
        acc.w += v * bf2f(w4.w);
    }
    float4 bd = *(const float4*)(b_dec + 4 * t);
    acc.x += bd.x; acc.y += bd.y; acc.z += bd.z; acc.w += bd.w;
    *(float4*)(recon + (size_t)r * K_DIM + 4 * t) = acc;
}

// ---------------- launch ----------------
extern "C" void kernel_launch(void* const* d_in, const int* in_sizes, int n_in,
                              void* d_out, int out_size, void* d_ws, size_t ws_size,
                              hipStream_t stream) {
    const float* x     = (const float*)d_in[0];
    const float* W_enc = (const float*)d_in[1];
    const float* b_enc = (const float*)d_in[2];
    const float* W_dec = (const float*)d_in[3];
    const float* b_dec = (const float*)d_in[4];
    float* recon = (float*)d_out;
    float* Z     = recon + (size_t)M_BATCH * K_DIM;   // z region of d_out (GEMM scratch, then final z)

    char* ws = (char*)d_ws;
    unsigned short* Wh  = (unsigned short*)(ws);                 // 33,554,432 B
    unsigned short* xh  = (unsigned short*)(ws + 33554432);      // 16,777,216 B
    unsigned short* WdT = (unsigned short*)(ws + 50331648);      // 33,554,432 B
    int*   cand = (int*)  (ws + 83886080);                       //  8,388,608 B
    int*   cnt  = (int*)  (ws + 92274688);                       //     32,768 B
    int*   seli = (int*)  (ws + 92307456);                       //  2,097,152 B
    float* selv = (float*)(ws + 94404608);                       //  2,097,152 B

    to_bf16<<<(N_LAT * K_DIM / 4 + 255) / 256, 256, 0, stream>>>(
        (const float4*)W_enc, Wh, N_LAT * K_DIM / 4);
    to_bf16<<<(M_BATCH * K_DIM / 4 + 255) / 256, 256, 0, stream>>>(
        (const float4*)x, xh, M_BATCH * K_DIM / 4);
    transpose_wdec<<<dim3(N_LAT / 64, K_DIM / 64), 256, 0, stream>>>(W_dec, WdT);

    enc_gemm<<<dim3(N_LAT / 128, M_BATCH / 128), 256, 0, stream>>>(xh, Wh, b_enc, Z);

    select_cand<<<M_BATCH, 256, 0, stream>>>(Z, cand, cnt);

    exact_topk<<<M_BATCH, 256, 0, stream>>>(x, W_enc, b_enc, cand, cnt, seli, selv);

    decode<<<M_BATCH, 256, 0, stream>>>(seli, selv, WdT, b_dec, recon, Z);
}

// Round 4
// 1499.358 us; speedup vs baseline: 1.3105x; 1.2238x over previous
//
#include <hip/hip_runtime.h>
#include <stdint.h>

// TopK SAE forward, MI355X/gfx950.
// bf16-MFMA approximate encoder (fp16 Z scratch) -> register-held single-pass
// candidate select (1024 linear bins, positive-only histogram, margin 0.015)
// -> exact fp64 recompute of ~77 candidates/row -> true top-64 (index
// tie-break) -> fused zero+scatter+sparse-decode with bf16 W_decT.

#define M_BATCH 8192
#define K_DIM   1024
#define N_LAT   16384
#define TOPK    64
#define CAND_CAP 256
#define MARGIN  0.015f

typedef float f32x4 __attribute__((ext_vector_type(4)));
typedef unsigned int u32x4 __attribute__((ext_vector_type(4)));
typedef short s16x8 __attribute__((ext_vector_type(8)));
typedef unsigned short u16x8 __attribute__((ext_vector_type(8)));

typedef __attribute__((address_space(3))) void       lds_void;
typedef const __attribute__((address_space(1))) void glb_void;

__device__ __forceinline__ void async_copy16(const void* g, void* l) {
    __builtin_amdgcn_global_load_lds((glb_void*)g, (lds_void*)l, 16, 0, 0);
}

__device__ __forceinline__ unsigned short f2bf(float f) {
    uint32_t u = __float_as_uint(f);
    uint32_t r = (u + 0x7FFFu + ((u >> 16) & 1u)) >> 16;   // RNE
    return (unsigned short)r;
}
__device__ __forceinline__ float bf2f(unsigned short h) {
    return __uint_as_float(((uint32_t)h) << 16);
}
__device__ __forceinline__ unsigned short f2h(float f) {
    _Float16 h = (_Float16)f;
    unsigned short u;
    __builtin_memcpy(&u, &h, 2);
    return u;
}
__device__ __forceinline__ float h2f(unsigned short u) {
    _Float16 h;
    __builtin_memcpy(&h, &u, 2);
    return (float)h;
}

// ---------------- K0a: fp32 -> bf16 conversion ----------------
__global__ void to_bf16(const float4* __restrict__ src, unsigned short* __restrict__ dst,
                        int nvec) {
    int i = blockIdx.x * blockDim.x + threadIdx.x;
    if (i < nvec) {
        float4 f = src[i];
        ushort4 o;
        o.x = f2bf(f.x); o.y = f2bf(f.y); o.z = f2bf(f.z); o.w = f2bf(f.w);
        *(ushort4*)(dst + (size_t)i * 4) = o;
    }
}

// ---------------- K0b: W_dec [1024,16384] fp32 -> W_decT [16384,1024] bf16 ----------------
__global__ void transpose_wdec(const float* __restrict__ Wd, unsigned short* __restrict__ WdT) {
    __shared__ float tile[64][65];
    int bj = blockIdx.x;
    int bi = blockIdx.y;
    int t = threadIdx.x;
    int tj = t & 63, ti4 = t >> 6;
    #pragma unroll
    for (int rr = 0; rr < 16; rr++) {
        int i = ti4 * 16 + rr;
        tile[i][tj] = Wd[(size_t)(bi * 64 + i) * N_LAT + bj * 64 + tj];
    }
    __syncthreads();
    int ti = t & 63, tj4 = t >> 6;
    #pragma unroll
    for (int rr = 0; rr < 16; rr++) {
        int j = tj4 * 16 + rr;
        WdT[(size_t)(bj * 64 + j) * K_DIM + bi * 64 + ti] = f2bf(tile[ti][j]);
    }
}

// ---------------- K1: bf16 MFMA encoder GEMM, fp16 output ----------------
__global__ __launch_bounds__(256, 3) void enc_gemm(
        const unsigned short* __restrict__ A,
        const unsigned short* __restrict__ B,
        const float* __restrict__ b_enc,
        unsigned short* __restrict__ Zh) {
    __shared__ unsigned short aT[128 * 32];
    __shared__ unsigned short bT[128 * 32];
    int bn = blockIdx.x;
    int bm = blockIdx.y;
    int t = threadIdx.x;
    int w = t >> 6, l = t & 63;
    int wm = (w >> 1) * 64, wn = (w & 1) * 64;
    int lm = l & 15, q = l >> 4;

    const unsigned short* gA = A + (size_t)(bm * 128) * K_DIM;
    const unsigned short* gB = B + (size_t)(bn * 128) * K_DIM;

    f32x4 acc[4][4];
    #pragma unroll
    for (int i = 0; i < 4; i++)
        #pragma unroll
        for (int j = 0; j < 4; j++) acc[i][j] = (f32x4)0.0f;

    int srow = t >> 2;
    int sk = (t & 3) * 8;

    for (int kt = 0; kt < K_DIM; kt += 32) {
        async_copy16(gA + (size_t)srow * K_DIM + kt + sk, &aT[t * 8]);
        async_copy16(gA + (size_t)(srow + 64) * K_DIM + kt + sk, &aT[2048 + t * 8]);
        async_copy16(gB + (size_t)srow * K_DIM + kt + sk, &bT[t * 8]);
        async_copy16(gB + (size_t)(srow + 64) * K_DIM + kt + sk, &bT[2048 + t * 8]);
        __syncthreads();

        s16x8 af[4], bf[4];
        #pragma unroll
        for (int mi = 0; mi < 4; mi++)
            af[mi] = *(const s16x8*)&aT[(wm + mi * 16 + lm) * 32 + q * 8];
        #pragma unroll
        for (int ni = 0; ni < 4; ni++)
            bf[ni] = *(const s16x8*)&bT[(wn + ni * 16 + lm) * 32 + q * 8];
        #pragma unroll
        for (int mi = 0; mi < 4; mi++)
            #pragma unroll
            for (int ni = 0; ni < 4; ni++)
                acc[mi][ni] = __builtin_amdgcn_mfma_f32_16x16x32_bf16(
                    af[mi], bf[ni], acc[mi][ni], 0, 0, 0);
        __syncthreads();
    }

    size_t gm0 = (size_t)bm * 128 + wm;
    size_t gn0 = (size_t)bn * 128 + wn;
    #pragma unroll
    for (int ni = 0; ni < 4; ni++) {
        size_t gn = gn0 + ni * 16 + lm;
        float bv = b_enc[gn];
        #pragma unroll
        for (int mi = 0; mi < 4; mi++) {
            size_t gmb = gm0 + mi * 16 + q * 4;
            #pragma unroll
            for (int r = 0; r < 4; r++)
                Zh[(gmb + r) * N_LAT + gn] = f2h(acc[mi][ni][r] + bv);
        }
    }
}

// ---------------- K2 v3: register-held single-pass candidate select ----------------
// One block / row. 32 KB fp16 row held in registers (u16x8[8] per thread).
// Positive-only histogram (1024 linear bins, 4 copies) avoids the bin-0
// atomic flood; parallel suffix scan finds the 64th-value bucket.
__global__ __launch_bounds__(256) void select_cand(
        const unsigned short* __restrict__ Zh, int* __restrict__ cand, int* __restrict__ cnt) {
    __shared__ int hist[4][1024];
    __shared__ int wsum[4];
    __shared__ int s_above, s_bin, s_cn;
    __shared__ float s_cut;

    int r = blockIdx.x;
    int t = threadIdx.x;
    int w = t >> 6, l = t & 63;

    int* hp = &hist[0][0];
    #pragma unroll
    for (int i = 0; i < 16; i++) hp[t + i * 256] = 0;
    __syncthreads();

    const u32x4* zg = (const u32x4*)(Zh + (size_t)r * N_LAT);
    u16x8 v[8];
    #pragma unroll
    for (int it = 0; it < 8; it++) {
        u32x4 raw = __builtin_nontemporal_load(&zg[t + it * 256]);
        u16x8 vv;
        __builtin_memcpy(&vv, &raw, 16);
        v[it] = vv;
        #pragma unroll
        for (int j = 0; j < 8; j++) {
            float f = h2f(vv[j]);
            if (f > 0.0f) {
                int b = min((int)(f * 64.0f), 1023);
                atomicAdd(&hist[w][b], 1);
            }
        }
    }
    __syncthreads();

    // merge 4 copies; thread t owns bins 4t..4t+3; g = group sum
    int g = 0;
    #pragma unroll
    for (int i = 0; i < 4; i++) {
        int b = 4 * t + i;
        int m = hist[0][b] + hist[1][b] + hist[2][b] + hist[3][b];
        hist[0][b] = m;
        g += m;
    }

    // block-wide inclusive prefix of g (low->high)
    int val = g;
    #pragma unroll
    for (int d = 1; d < 64; d <<= 1) {
        int n = __shfl_up(val, d, 64);
        if (l >= d) val += n;
    }
    if (l == 63) wsum[w] = val;
    __syncthreads();
    int off = 0;
    for (int i = 0; i < w; i++) off += wsum[i];
    int total = wsum[0] + wsum[1] + wsum[2] + wsum[3];
    int incl = val + off;
    int above = total - incl;                      // strictly above this thread's group
    if (above < TOPK && above + g >= TOPK) {       // exactly one thread
        s_above = above;
        s_bin = t;
    }
    __syncthreads();
    if (t == 0) {
        int c = s_above;
        int b = s_bin * 4 + 3;
        for (; b > s_bin * 4; b--) {
            if (c + hist[0][b] >= TOPK) break;
            c += hist[0][b];
        }
        s_cut = (float)b * (1.0f / 64.0f) - MARGIN;
        s_cn = 0;
    }
    __syncthreads();

    float cut = s_cut;
    #pragma unroll
    for (int it = 0; it < 8; it++) {
        #pragma unroll
        for (int j = 0; j < 8; j++) {
            float f = h2f(v[it][j]);
            if (f >= cut) {
                int p = atomicAdd(&s_cn, 1);
                if (p < CAND_CAP) cand[(size_t)r * CAND_CAP + p] = (t + it * 256) * 8 + j;
            }
        }
    }
    __syncthreads();
    if (t == 0) cnt[r] = min(s_cn, CAND_CAP);
}

// ---------------- K3: exact fp64 recompute + true top-64 (float4 gathers) ----------------
__global__ void exact_topk(const float* __restrict__ x, const float* __restrict__ W,
                           const float* __restrict__ b_enc,
                           const int* __restrict__ cand, const int* __restrict__ cnt,
                           int* __restrict__ seli, float* __restrict__ selv) {
    int r = blockIdx.x;
    __shared__ float xs[K_DIM];
    __shared__ double vals[CAND_CAP];
    __shared__ int ns[CAND_CAP];
    int t = threadIdx.x;
    ((float4*)xs)[t] = ((const float4*)(x + (size_t)r * K_DIM))[t];
    int n_c = cnt[r];
    if (t < n_c) ns[t] = cand[(size_t)r * CAND_CAP + t];
    __syncthreads();

    int w = t >> 6, l = t & 63;
    for (int c = w; c < n_c; c += 4) {
        const float4* wr = (const float4*)(W + (size_t)ns[c] * K_DIM);
        double s = 0.0;
        #pragma unroll
        for (int i = 0; i < 4; i++) {
            float4 wv = wr[l + i * 64];
            float4 xv = ((const float4*)xs)[l + i * 64];
            s += (double)xv.x * wv.x + (double)xv.y * wv.y
               + (double)xv.z * wv.z + (double)xv.w * wv.w;
        }
        for (int o = 32; o > 0; o >>= 1) s += __shfl_down(s, o, 64);
        if (l == 0) vals[c] = s + (double)b_enc[ns[c]];
    }
    __syncthreads();

    if (t < n_c) {
        double v = vals[t];
        int n = ns[t];
        int rank = 0;
        for (int j = 0; j < n_c; j++) {
            double vj = vals[j];
            if (vj > v || (vj == v && ns[j] < n)) rank++;   // lax.top_k tie-break
        }
        if (rank < TOPK) {
            seli[(size_t)r * TOPK + rank] = n;
            selv[(size_t)r * TOPK + rank] = (float)(v > 0.0 ? v : 0.0);
        }
    }
}

// ---------------- K4: fused zero-z + scatter + sparse decoder ----------------
__global__ void decode(const int* __restrict__ seli, const float* __restrict__ selv,
                       const unsigned short* __restrict__ WdT,
                       const float* __restrict__ b_dec,
                       float* __restrict__ recon, float* __restrict__ Z) {
    int r = blockIdx.x;
    __shared__ int is[TOPK];
    __shared__ float vs[TOPK];
    int t = threadIdx.x;
    if (t < TOPK) {
        is[t] = seli[(size_t)r * TOPK + t];
        vs[t] = selv[(size_t)r * TOPK + t];
    }
    // zero this row's z (streaming stores)
    f32x4* zr4 = (f32x4*)(Z + (size_t)r * N_LAT);
    f32x4 z4 = (f32x4)0.0f;
    #pragma unroll
    for (int it = 0; it < 16; it++)
        __builtin_nontemporal_store(z4, &zr4[t + it * 256]);
    __syncthreads();
    if (t < TOPK) Z[(size_t)r * N_LAT + is[t]] = vs[t];

    f32x4 acc = (f32x4)0.0f;
    #pragma unroll 4
    for (int j = 0; j < TOPK; j++) {
        const unsigned short* wr = WdT + (size_t)is[j] * K_DIM;
        float v = vs[j];
        ushort4 w4 = *(const ushort4*)(wr + 4 * t);
        acc.x += v * bf2f(w4.x);
        acc.y += v * bf2f(w4.y);
        acc.z += v * bf2f(w4.z);
        acc.w += v * bf2f(w4.w);
    }
    f32x4 bd = *(const f32x4*)(b_dec + 4 * t);
    acc += bd;
    __builtin_nontemporal_store(acc, (f32x4*)(recon + (size_t)r * K_DIM + 4 * t));
}

// ---------------- launch ----------------
extern "C" void kernel_launch(void* const* d_in, const int* in_sizes, int n_in,
                              void* d_out, int out_size, void* d_ws, size_t ws_size,
                              hipStream_t stream) {
    const float* x     = (const float*)d_in[0];
    const float* W_enc = (const float*)d_in[1];
    const float* b_enc = (const float*)d_in[2];
    const float* W_dec = (const float*)d_in[3];
    const float* b_dec = (const float*)d_in[4];
    float* recon = (float*)d_out;
    float* Z     = recon + (size_t)M_BATCH * K_DIM;     // fp32 z output region
    unsigned short* Zh = (unsigned short*)Z;            // fp16 scratch inside z region

    char* ws = (char*)d_ws;
    unsigned short* Wh  = (unsigned short*)(ws);                 // 33,554,432 B
    unsigned short* xh  = (unsigned short*)(ws + 33554432);      // 16,777,216 B
    unsigned short* WdT = (unsigned short*)(ws + 50331648);      // 33,554,432 B
    int*   cand = (int*)  (ws + 83886080);                       //  8,388,608 B
    int*   cnt  = (int*)  (ws + 92274688);                       //     32,768 B
    int*   seli = (int*)  (ws + 92307456);                       //  2,097,152 B
    float* selv = (float*)(ws + 94404608);                       //  2,097,152 B

    to_bf16<<<(N_LAT * K_DIM / 4 + 255) / 256, 256, 0, stream>>>(
        (const float4*)W_enc, Wh, N_LAT * K_DIM / 4);
    to_bf16<<<(M_BATCH * K_DIM / 4 + 255) / 256, 256, 0, stream>>>(
        (const float4*)x, xh, M_BATCH * K_DIM / 4);
    transpose_wdec<<<dim3(N_LAT / 64, K_DIM / 64), 256, 0, stream>>>(W_dec, WdT);

    enc_gemm<<<dim3(N_LAT / 128, M_BATCH / 128), 256, 0, stream>>>(xh, Wh, b_enc, Zh);

    select_cand<<<M_BATCH, 256, 0, stream>>>(Zh, cand, cnt);

    exact_topk<<<M_BATCH, 256, 0, stream>>>(x, W_enc, b_enc, cand, cnt, seli, selv);

    decode<<<M_BATCH, 256, 0, stream>>>(seli, selv, WdT, b_dec, recon, Z);
}